// Round 1
// baseline (18.096 us; speedup 1.0000x reference)
//
#include <hip/hip_runtime.h>

#define IMG 512
#define PS  28      // patch spatial size
#define KS  33
#define PAD 16
#define RT  16      // output rows per block tile

// ---------------------------------------------------------------------------
// Prep: for each output coordinate y in [0,512), the 33-tap window over the
// nearest-upsampled signal touches at most 3 source cells. Collapse the 1D
// kernel (row-sums of the separable 2D blur) into {base, w0, w1, w2}.
// Table is shared between rows and columns (img_h == img_w, ih == iw).
// ---------------------------------------------------------------------------
__global__ void prep_weights(const float* __restrict__ blur_w,
                             float4* __restrict__ wc) {
    __shared__ float k1[KS];
    int t = threadIdx.x;
    if (t < KS) {
        float s = 0.f;
        for (int j = 0; j < KS; ++j) s += blur_w[t * KS + j];
        k1[t] = s;                       // k1[i] = row sum = 1D gaussian tap
    }
    __syncthreads();
    int y = t;                           // single block of 512 threads
    if (y >= IMG) return;

    int pos0 = y - PAD; if (pos0 < 0) pos0 = 0;
    int smin = (pos0 * PS) >> 9;         // floor(pos*28/512)
    int base = smin > PS - 3 ? PS - 3 : smin;   // keep base+2 <= 27

    float w0 = 0.f, w1 = 0.f, w2 = 0.f;
    for (int k = 0; k < KS; ++k) {
        int pos = y + k - PAD;
        if (pos < 0 || pos >= IMG) continue;     // zero padding
        int s = (pos * PS) >> 9;
        int d = s - base;                        // in {0,1,2}
        float kv = k1[k];
        w0 += (d == 0) ? kv : 0.f;
        w1 += (d == 1) ? kv : 0.f;
        w2 += (d == 2) ? kv : 0.f;
    }
    wc[y] = make_float4(__int_as_float(base), w0, w1, w2);
}

// ---------------------------------------------------------------------------
// Main: one block = (image b, 16 output rows). Stage patch (28x28) in LDS,
// build M[16][28] = row-blurred patch rows, then each thread writes 8 rows
// of one float4 column-quad (coalesced 1KB/wave stores).
// ---------------------------------------------------------------------------
__global__ __launch_bounds__(256) void anomaly_main(
        const float* __restrict__ p_in,
        const float4* __restrict__ wc,
        float* __restrict__ out,
        int tiles_per_img) {
    __shared__ float  P[PS * PS];     // 784 floats
    __shared__ float4 WY[RT];
    __shared__ float  M[RT * PS];     // 448 floats

    int t    = threadIdx.x;
    int b    = blockIdx.x / tiles_per_img;
    int tile = blockIdx.x - b * tiles_per_img;
    int y0   = tile * RT;

    if (t < (PS * PS) / 4)            // 196 float4 loads
        ((float4*)P)[t] = ((const float4*)(p_in + (size_t)b * PS * PS))[t];
    if (t < RT) WY[t] = wc[y0 + t];
    __syncthreads();

    // M[r][sx] = wy0*P[base][sx] + wy1*P[base+1][sx] + wy2*P[base+2][sx]
    for (int i = t; i < RT * PS; i += 256) {
        int r = i / PS, sx = i - r * PS;
        float4 w  = WY[r];
        int   byy = __float_as_int(w.x);
        M[i] = w.y * P[byy * PS + sx]
             + w.z * P[(byy + 1) * PS + sx]
             + w.w * P[(byy + 2) * PS + sx];
    }
    __syncthreads();

    // thread -> column quad q (x0 = 4q), row-half (8 rows each)
    int q    = t & 127;
    int half = t >> 7;
    int x0   = q * 4;

    float4 wx[4];
    int    bx[4];
#pragma unroll
    for (int j = 0; j < 4; ++j) {
        wx[j] = wc[x0 + j];
        bx[j] = __float_as_int(wx[j].x);
    }

    float* orow = out + ((size_t)b * IMG + (y0 + half * 8)) * IMG + x0;
#pragma unroll
    for (int r = 0; r < 8; ++r) {
        const float* m = &M[(half * 8 + r) * PS];
        float4 acc;
        acc.x = m[bx[0]] * wx[0].y + m[bx[0] + 1] * wx[0].z + m[bx[0] + 2] * wx[0].w;
        acc.y = m[bx[1]] * wx[1].y + m[bx[1] + 1] * wx[1].z + m[bx[1] + 2] * wx[1].w;
        acc.z = m[bx[2]] * wx[2].y + m[bx[2] + 1] * wx[2].z + m[bx[2] + 2] * wx[2].w;
        acc.w = m[bx[3]] * wx[3].y + m[bx[3] + 1] * wx[3].z + m[bx[3] + 2] * wx[3].w;
        *(float4*)(orow + (size_t)r * IMG) = acc;
    }
}

extern "C" void kernel_launch(void* const* d_in, const int* in_sizes, int n_in,
                              void* d_out, int out_size, void* d_ws, size_t ws_size,
                              hipStream_t stream) {
    const float* patch = (const float*)d_in[0];
    const float* blur  = (const float*)d_in[1];
    float*       out   = (float*)d_out;
    float4*      wc    = (float4*)d_ws;          // 512 * 16B = 8 KB scratch

    int B = in_sizes[0] / (PS * PS);             // 32

    prep_weights<<<1, IMG, 0, stream>>>(blur, wc);

    int tiles = IMG / RT;                        // 32
    anomaly_main<<<B * tiles, 256, 0, stream>>>(patch, wc, out, tiles);
}

// Round 2
// 17.795 us; speedup vs baseline: 1.0169x; 1.0169x over previous
//
#include <hip/hip_runtime.h>

#define IMG 512
#define PS  28      // patch spatial size
#define KS  33
#define PAD 16
#define RT  16      // output rows per block tile

// Single fused kernel. One block = (image b, 16 output rows).
//
// Math: blur kernel is separable (k1 outer k1); k1 recovered exactly as row
// sums of blur_w (since sum k1 == 1). Conv input is nearest-upsampled
// 28->512, i.e. piecewise constant with block width ~18.3, so a 33-tap
// window spans at most 3 source cells: out = Wy * P * Wx^T with <=3
// nonzeros per row of Wy/Wx. Table W[y] = {base, w0, w1, w2} is identical
// for rows and columns (ih == iw); each block rebuilds it in LDS (~70
// VALU ops/thread, amortized against 128 B/thread of stores).
__global__ __launch_bounds__(256) void anomaly_fused(
        const float* __restrict__ p_in,
        const float* __restrict__ blur_w,
        float* __restrict__ out,
        int tiles_per_img) {
    __shared__ float  k1[KS];
    __shared__ float4 W[IMG];         // 8 KB  {base(bits), w0, w1, w2}
    __shared__ float  P[PS * PS];     // 3.1 KB patch
    __shared__ float  M[RT * PS];     // 1.8 KB row-blurred rows

    int t    = threadIdx.x;
    int b    = blockIdx.x / tiles_per_img;
    int tile = blockIdx.x - b * tiles_per_img;
    int y0   = tile * RT;

    // phase A: k1 row sums + patch load
    if (t < KS) {
        float s = 0.f;
#pragma unroll
        for (int j = 0; j < KS; ++j) s += blur_w[t * KS + j];
        k1[t] = s;
    }
    if (t < (PS * PS) / 4)            // 196 float4 loads
        ((float4*)P)[t] = ((const float4*)(p_in + (size_t)b * PS * PS))[t];
    __syncthreads();

    // phase B: collapse 33-tap window onto <=3 source cells, per coordinate
    for (int y = t; y < IMG; y += 256) {
        int pos0 = y - PAD; if (pos0 < 0) pos0 = 0;
        int smin = (pos0 * PS) >> 9;                 // floor(pos*28/512)
        int base = smin > PS - 3 ? PS - 3 : smin;    // keep base+2 <= 27
        float w0 = 0.f, w1 = 0.f, w2 = 0.f;
#pragma unroll
        for (int k = 0; k < KS; ++k) {
            int pos = y + k - PAD;
            if (pos < 0 || pos >= IMG) continue;     // zero padding
            int d = ((pos * PS) >> 9) - base;        // in {0,1,2}
            float kv = k1[k];
            w0 += (d == 0) ? kv : 0.f;
            w1 += (d == 1) ? kv : 0.f;
            w2 += (d == 2) ? kv : 0.f;
        }
        W[y] = make_float4(__int_as_float(base), w0, w1, w2);
    }
    __syncthreads();

    // phase C: M[r][sx] = wy0*P[by][sx] + wy1*P[by+1][sx] + wy2*P[by+2][sx]
    for (int i = t; i < RT * PS; i += 256) {
        int r = i / PS, sx = i - r * PS;
        float4 w  = W[y0 + r];
        int   byy = __float_as_int(w.x);
        M[i] = w.y * P[byy * PS + sx]
             + w.z * P[(byy + 1) * PS + sx]
             + w.w * P[(byy + 2) * PS + sx];
    }
    __syncthreads();

    // phase D: each thread writes 8 rows of one float4 column-quad
    int q    = t & 127;
    int half = t >> 7;
    int x0   = q * 4;

    float4 wx[4];
    int    bx[4];
#pragma unroll
    for (int j = 0; j < 4; ++j) {
        wx[j] = W[x0 + j];
        bx[j] = __float_as_int(wx[j].x);
    }

    float* orow = out + ((size_t)b * IMG + (y0 + half * 8)) * IMG + x0;
#pragma unroll
    for (int r = 0; r < 8; ++r) {
        const float* m = &M[(half * 8 + r) * PS];
        float4 acc;
        acc.x = m[bx[0]] * wx[0].y + m[bx[0] + 1] * wx[0].z + m[bx[0] + 2] * wx[0].w;
        acc.y = m[bx[1]] * wx[1].y + m[bx[1] + 1] * wx[1].z + m[bx[1] + 2] * wx[1].w;
        acc.z = m[bx[2]] * wx[2].y + m[bx[2] + 1] * wx[2].z + m[bx[2] + 2] * wx[2].w;
        acc.w = m[bx[3]] * wx[3].y + m[bx[3] + 1] * wx[3].z + m[bx[3] + 2] * wx[3].w;
        *(float4*)(orow + (size_t)r * IMG) = acc;
    }
}

extern "C" void kernel_launch(void* const* d_in, const int* in_sizes, int n_in,
                              void* d_out, int out_size, void* d_ws, size_t ws_size,
                              hipStream_t stream) {
    const float* patch = (const float*)d_in[0];
    const float* blur  = (const float*)d_in[1];
    float*       out   = (float*)d_out;

    int B = in_sizes[0] / (PS * PS);             // 32
    int tiles = IMG / RT;                        // 32

    anomaly_fused<<<B * tiles, 256, 0, stream>>>(patch, blur, out, tiles);
}

// Round 3
// 14.535 us; speedup vs baseline: 1.2450x; 1.2243x over previous
//
#include <hip/hip_runtime.h>

#define IMG 512
#define PS  28      // patch spatial size
#define KS  33
#define PAD 16
#define RT  8       // output rows per block tile
#define TILES (IMG / RT)   // 64 tiles/image

// out = Wy * (P * Wx^T): nearest-upsample + separable 33-tap blur collapses
// to <=3 taps per axis (window spans <=3 source cells of width ~18.3).
// Weights in closed form from prefix sums of k1 (k1 = row sums of blur_w):
//   cell s covers pos in [C(s), C(s+1)), C(s) = ceil(512 s / 28)
//   w_d(y) = S[clamp(C(b+d+1)-y+16)] - S[clamp(C(b+d)-y+16)],  S = prefix(k1)
// Zero padding handled automatically by the clamp to [0, 33].
__device__ __forceinline__ int base_of(int y) {
    int p0 = y - PAD; if (p0 < 0) p0 = 0;
    int b = (p0 * PS) >> 9;              // floor(p0*28/512)
    return b > PS - 3 ? PS - 3 : b;
}

__device__ __forceinline__ float3 collapse(int y, int base, const float* S) {
    float w[3];
#pragma unroll
    for (int d = 0; d < 3; ++d) {
        int s  = base + d;
        int lo = (512 * s + 27) / 28 - y + PAD;        // C(s)   - y + 16
        int hi = (512 * (s + 1) + 27) / 28 - y + PAD;  // C(s+1) - y + 16
        lo = min(max(lo, 0), KS);
        hi = min(max(hi, 0), KS);
        w[d] = S[hi] - S[lo];
    }
    return make_float3(w[0], w[1], w[2]);
}

__global__ __launch_bounds__(256) void anomaly_fused(
        const float* __restrict__ p_in,
        const float* __restrict__ blur_w,
        float* __restrict__ out) {
    __shared__ float  S[KS + 1];                    // exclusive prefix of k1
    __shared__ __align__(16) float P[PS * PS];      // 3.1 KB patch
    __shared__ float4 WY[RT];                       // per-row {base,w0,w1,w2}
    __shared__ __align__(16) float N[4][IMG];       // 8 KB col-blurred rows

    int t    = threadIdx.x;
    int b    = blockIdx.x >> 6;                     // / TILES
    int tile = blockIdx.x & (TILES - 1);
    int y0   = tile * RT;
    int smin = base_of(y0);                         // first source row needed

    // ---- phase A: k1 row sums (lanes 0..32) + patch load (float4 coalesced)
    if (t < KS) {
        const float* row = blur_w + t * KS;
        float s = 0.f;
#pragma unroll
        for (int j = 0; j < KS; ++j) s += row[j];
        S[t + 1] = s;                               // k1[t], pre-prefix
    }
    if (t < (PS * PS) / 4)
        ((float4*)P)[t] = ((const float4*)(p_in + (size_t)b * PS * PS))[t];
    __syncthreads();

    // ---- serial prefix over 33 taps (cheap: ~150 cyc dependent adds)
    if (t == 0) {
        float acc = 0.f;
        S[0] = 0.f;
        for (int k = 0; k < KS; ++k) { acc += S[k + 1]; S[k + 1] = acc; }
    }
    __syncthreads();

    // ---- phase B: y-weights for this tile's 8 rows
    if (t < RT) {
        int by = base_of(y0 + t);
        float3 w = collapse(y0 + t, by, S);
        WY[t] = make_float4(__int_as_float(by), w.x, w.y, w.z);
    }
    // ---- phase C: N[i][x] = column-blur of source rows smin..smin+3
    for (int x = t; x < IMG; x += 256) {
        int bx = base_of(x);
        float3 w = collapse(x, bx, S);
#pragma unroll
        for (int i = 0; i < 4; ++i) {
            int sr = smin + i; if (sr > PS - 1) sr = PS - 1;  // unused if OOB
            const float* pr = P + sr * PS + bx;
            N[i][x] = w.x * pr[0] + w.y * pr[1] + w.z * pr[2];
        }
    }
    __syncthreads();

    // ---- phase D: each thread emits 4 rows of one float4 column-quad
    int q    = t & 127;
    int half = t >> 7;
    int x0   = q * 4;

    float* obase = out + ((size_t)b * IMG + y0) * IMG + x0;
#pragma unroll
    for (int i = 0; i < 4; ++i) {
        int r = half * 4 + i;
        float4 wv = WY[r];                          // wave-uniform broadcast
        int dy = __float_as_int(wv.x) - smin;       // 0 or 1
        float4 a0 = *(const float4*)&N[dy][x0];
        float4 a1 = *(const float4*)&N[dy + 1][x0];
        float4 a2 = *(const float4*)&N[dy + 2][x0];
        float4 acc;
        acc.x = wv.y * a0.x + wv.z * a1.x + wv.w * a2.x;
        acc.y = wv.y * a0.y + wv.z * a1.y + wv.w * a2.y;
        acc.z = wv.y * a0.z + wv.z * a1.z + wv.w * a2.z;
        acc.w = wv.y * a0.w + wv.z * a1.w + wv.w * a2.w;
        *(float4*)(obase + (size_t)r * IMG) = acc;
    }
}

extern "C" void kernel_launch(void* const* d_in, const int* in_sizes, int n_in,
                              void* d_out, int out_size, void* d_ws, size_t ws_size,
                              hipStream_t stream) {
    const float* patch = (const float*)d_in[0];
    const float* blur  = (const float*)d_in[1];
    float*       out   = (float*)d_out;

    int B = in_sizes[0] / (PS * PS);                // 32 images
    anomaly_fused<<<B * TILES, 256, 0, stream>>>(patch, blur, out);
}

// Round 4
// 13.806 us; speedup vs baseline: 1.3108x; 1.0528x over previous
//
#include <hip/hip_runtime.h>

#define IMG 512
#define PS  28      // patch spatial size
#define KS  33
#define PAD 16
#define RT  16      // output rows per block tile
#define TILES (IMG / RT)   // 32 tiles/image

// out = Wy * (P * Wx^T): nearest-upsample + separable 33-tap blur collapses
// to <=3 taps per axis (window spans <=3 source cells of width ~18.3).
// Weights in closed form from prefix sums of k1 (k1 = row sums of blur_w):
//   cell s covers pos in [C(s), C(s+1)), C(s) = ceil(512 s / 28)
//   w_d(y) = S[clamp(C(b+d+1)-y+16)] - S[clamp(C(b+d)-y+16)],  S = prefix(k1)
// A 16-row output tile needs only 4 staged source rows (smin..smin+3), and
// per-row y-weights fold into a 4-tap vector u[0..3] relative to smin
// (dy = base(y)-smin is 0 or 1), so phase D is pure reg FMA on 4 float4s.
__device__ __forceinline__ int base_of(int y) {
    int p0 = y - PAD; if (p0 < 0) p0 = 0;
    int b = (p0 * PS) >> 9;              // floor(p0*28/512)
    return b > PS - 3 ? PS - 3 : b;
}

__device__ __forceinline__ float3 collapse(int y, int base, const float* S) {
    float w[3];
#pragma unroll
    for (int d = 0; d < 3; ++d) {
        int s  = base + d;
        int lo = (512 * s + 27) / 28 - y + PAD;        // C(s)   - y + 16
        int hi = (512 * (s + 1) + 27) / 28 - y + PAD;  // C(s+1) - y + 16
        lo = min(max(lo, 0), KS);
        hi = min(max(hi, 0), KS);
        w[d] = S[hi] - S[lo];
    }
    return make_float3(w[0], w[1], w[2]);
}

__global__ __launch_bounds__(256) void anomaly_fused(
        const float* __restrict__ p_in,
        const float* __restrict__ blur_w,
        float* __restrict__ out) {
    __shared__ float  S[KS + 1];                    // exclusive prefix of k1
    __shared__ __align__(16) float P[PS * PS];      // 3.1 KB patch
    __shared__ float4 WY[RT];                       // per-row 4-tap u vs smin
    __shared__ __align__(16) float N[4][IMG];       // 8 KB col-blurred rows

    int t    = threadIdx.x;
    int b    = blockIdx.x >> 5;                     // / TILES
    int tile = blockIdx.x & (TILES - 1);
    int y0   = tile * RT;
    int smin = base_of(y0);                         // first source row needed

    // ---- phase A: k1 row sums (lanes 0..32, one wave) + patch load
    if (t < KS) {
        const float* row = blur_w + t * KS;
        float s = 0.f;
#pragma unroll
        for (int j = 0; j < KS; ++j) s += row[j];
        S[t + 1] = s;                               // k1[t], pre-prefix
    }
    if (t < (PS * PS) / 4)
        ((float4*)P)[t] = ((const float4*)(p_in + (size_t)b * PS * PS))[t];
    __syncthreads();

    // ---- serial prefix over 33 taps (~150 dependent-add cycles, once/block)
    if (t == 0) {
        float acc = 0.f;
        S[0] = 0.f;
        for (int k = 0; k < KS; ++k) { acc += S[k + 1]; S[k + 1] = acc; }
    }
    __syncthreads();

    // ---- phase B: per-row 4-tap weights relative to smin (dy in {0,1})
    if (t < RT) {
        int by = base_of(y0 + t);
        float3 w = collapse(y0 + t, by, S);
        int  dy = by - smin;
        float u0 = dy ? 0.f : w.x;
        float u1 = dy ? w.x : w.y;
        float u2 = dy ? w.y : w.z;
        float u3 = dy ? w.z : 0.f;
        WY[t] = make_float4(u0, u1, u2, u3);
    }
    // ---- phase C: N[i][x] = column-blur of source rows smin..smin+3
    for (int x = t; x < IMG; x += 256) {
        int bx = base_of(x);
        float3 w = collapse(x, bx, S);
#pragma unroll
        for (int i = 0; i < 4; ++i) {
            int sr = smin + i; if (sr > PS - 1) sr = PS - 1;  // unused if OOB
            const float* pr = P + sr * PS + bx;
            N[i][x] = w.x * pr[0] + w.y * pr[1] + w.z * pr[2];
        }
    }
    __syncthreads();

    // ---- phase D: read 4 float4 ONCE, emit 8 rows of one column-quad
    int q    = t & 127;
    int half = t >> 7;
    int x0   = q * 4;

    float4 a0 = *(const float4*)&N[0][x0];
    float4 a1 = *(const float4*)&N[1][x0];
    float4 a2 = *(const float4*)&N[2][x0];
    float4 a3 = *(const float4*)&N[3][x0];

    float* obase = out + ((size_t)b * IMG + y0 + half * 8) * IMG + x0;
#pragma unroll
    for (int r = 0; r < 8; ++r) {
        float4 u = WY[half * 8 + r];                // wave-uniform broadcast
        float4 acc;
        acc.x = u.x * a0.x + u.y * a1.x + u.z * a2.x + u.w * a3.x;
        acc.y = u.x * a0.y + u.y * a1.y + u.z * a2.y + u.w * a3.y;
        acc.z = u.x * a0.z + u.y * a1.z + u.z * a2.z + u.w * a3.z;
        acc.w = u.x * a0.w + u.y * a1.w + u.z * a2.w + u.w * a3.w;
        *(float4*)(obase + (size_t)r * IMG) = acc;
    }
}

extern "C" void kernel_launch(void* const* d_in, const int* in_sizes, int n_in,
                              void* d_out, int out_size, void* d_ws, size_t ws_size,
                              hipStream_t stream) {
    const float* patch = (const float*)d_in[0];
    const float* blur  = (const float*)d_in[1];
    float*       out   = (float*)d_out;

    int B = in_sizes[0] / (PS * PS);                // 32 images
    anomaly_fused<<<B * TILES, 256, 0, stream>>>(patch, blur, out);
}

// Round 5
// 13.644 us; speedup vs baseline: 1.3263x; 1.0119x over previous
//
#include <hip/hip_runtime.h>

#define IMG 512
#define PS  28      // patch spatial size
#define KS  33
#define PAD 16
#define RT  16      // output rows per block tile
#define TILES (IMG / RT)   // 32 tiles/image

// out = Wy * (P * Wx^T): nearest-upsample + separable 33-tap blur collapses
// to <=3 taps per axis (window spans <=3 source cells of width ~18.3).
// k1 recovered from one COLUMN of blur_w: K[i][j]=k1[i]k1[j] =>
//   k1[i] = K[i][16] / sqrt(K[16][16])          (1 load/lane, no 33x33 scan)
// Prefix S of k1 built with a 6-step wave shfl_up scan (no serial loop).
// Weights in closed form from S:
//   cell s covers pos in [C(s), C(s+1)), C(s) = ceil(512 s / 28)
//   w_d(y) = S[clamp(C(b+d+1)-y+16)] - S[clamp(C(b+d)-y+16)]
// A 16-row tile needs 4 staged source rows; per-row y-weights fold into a
// 4-tap vector u[0..3] relative to smin, so phase D is pure reg FMA.
__device__ __forceinline__ int base_of(int y) {
    int p0 = y - PAD; if (p0 < 0) p0 = 0;
    int b = (p0 * PS) >> 9;              // floor(p0*28/512)
    return b > PS - 3 ? PS - 3 : b;
}

__device__ __forceinline__ float3 collapse(int y, int base, const float* S) {
    float w[3];
#pragma unroll
    for (int d = 0; d < 3; ++d) {
        int s  = base + d;
        int lo = (512 * s + 27) / 28 - y + PAD;        // C(s)   - y + 16
        int hi = (512 * (s + 1) + 27) / 28 - y + PAD;  // C(s+1) - y + 16
        lo = min(max(lo, 0), KS);
        hi = min(max(hi, 0), KS);
        w[d] = S[hi] - S[lo];
    }
    return make_float3(w[0], w[1], w[2]);
}

__global__ __launch_bounds__(256) void anomaly_fused(
        const float* __restrict__ p_in,
        const float* __restrict__ blur_w,
        float* __restrict__ out) {
    __shared__ float  S[KS + 1];                    // prefix of k1 (S[0]=0)
    __shared__ __align__(16) float P[PS * PS];      // 3.1 KB patch
    __shared__ float4 WY[RT];                       // per-row 4-tap u vs smin
    __shared__ __align__(16) float N[4][IMG];       // 8 KB col-blurred rows

    int t    = threadIdx.x;
    int b    = blockIdx.x >> 5;                     // / TILES
    int tile = blockIdx.x & (TILES - 1);
    int y0   = tile * RT;
    int smin = base_of(y0);                         // first source row needed

    // ---- phase A: k1 from column 16 + wave-scan prefix (wave 0 only),
    //      patch load on lanes 0..195 (independent, overlaps the scan)
    if (t < 64) {
        float v = (t < KS) ? blur_w[t * KS + 16] : 0.f;   // K[t][16]
        float c = __shfl(v, 16);                    // K[16][16] = k1[16]^2
        float k = v / sqrtf(c);                     // k1[t]
        float s = k;
#pragma unroll
        for (int d = 1; d <= 32; d <<= 1) {         // inclusive scan, 6 steps
            float o = __shfl_up(s, (unsigned)d);
            if (t >= d) s += o;
        }
        if (t < KS)  S[t + 1] = s;
        if (t == 33) S[0] = 0.f;
    }
    if (t < (PS * PS) / 4)                          // 196 float4 loads
        ((float4*)P)[t] = ((const float4*)(p_in + (size_t)b * PS * PS))[t];
    __syncthreads();

    // ---- phase B: per-row 4-tap weights relative to smin (dy in {0,1})
    if (t < RT) {
        int by = base_of(y0 + t);
        float3 w = collapse(y0 + t, by, S);
        int  dy = by - smin;
        float u0 = dy ? 0.f : w.x;
        float u1 = dy ? w.x : w.y;
        float u2 = dy ? w.y : w.z;
        float u3 = dy ? w.z : 0.f;
        WY[t] = make_float4(u0, u1, u2, u3);
    }
    // ---- phase C: N[i][x] = column-blur of source rows smin..smin+3
#pragma unroll
    for (int xi = 0; xi < 2; ++xi) {
        int x = t + xi * 256;
        int bx = base_of(x);
        float3 w = collapse(x, bx, S);
#pragma unroll
        for (int i = 0; i < 4; ++i) {
            int sr = smin + i; if (sr > PS - 1) sr = PS - 1;  // unused if OOB
            const float* pr = P + sr * PS + bx;
            N[i][x] = w.x * pr[0] + w.y * pr[1] + w.z * pr[2];
        }
    }
    __syncthreads();

    // ---- phase D: read 4 float4 ONCE, emit 8 rows of one column-quad
    int q    = t & 127;
    int half = t >> 7;
    int x0   = q * 4;

    float4 a0 = *(const float4*)&N[0][x0];
    float4 a1 = *(const float4*)&N[1][x0];
    float4 a2 = *(const float4*)&N[2][x0];
    float4 a3 = *(const float4*)&N[3][x0];

    float* obase = out + ((size_t)b * IMG + y0 + half * 8) * IMG + x0;
#pragma unroll
    for (int r = 0; r < 8; ++r) {
        float4 u = WY[half * 8 + r];                // wave-uniform broadcast
        float4 acc;
        acc.x = u.x * a0.x + u.y * a1.x + u.z * a2.x + u.w * a3.x;
        acc.y = u.x * a0.y + u.y * a1.y + u.z * a2.y + u.w * a3.y;
        acc.z = u.x * a0.z + u.y * a1.z + u.z * a2.z + u.w * a3.z;
        acc.w = u.x * a0.w + u.y * a1.w + u.z * a2.w + u.w * a3.w;
        *(float4*)(obase + (size_t)r * IMG) = acc;
    }
}

extern "C" void kernel_launch(void* const* d_in, const int* in_sizes, int n_in,
                              void* d_out, int out_size, void* d_ws, size_t ws_size,
                              hipStream_t stream) {
    const float* patch = (const float*)d_in[0];
    const float* blur  = (const float*)d_in[1];
    float*       out   = (float*)d_out;

    int B = in_sizes[0] / (PS * PS);                // 32 images
    anomaly_fused<<<B * TILES, 256, 0, stream>>>(patch, blur, out);
}

// Round 7
// 13.392 us; speedup vs baseline: 1.3513x; 1.0188x over previous
//
#include <hip/hip_runtime.h>

#define IMG 512
#define PS  28      // patch spatial size
#define KS  33
#define PAD 16
#define RT  16      // output rows per block tile
#define TILES (IMG / RT)   // 32 tiles/image

typedef float vf4 __attribute__((ext_vector_type(4)));  // clang vector for nt-store

// out = Wy * (P * Wx^T): nearest-upsample + separable 33-tap blur collapses
// to <=3 taps per axis (a 33-tap window spans <=3 source cells of width
// ~18.3). k1 recovered from one COLUMN of blur_w (K[i][j]=k1[i]k1[j] =>
// k1[i]=K[i][16]/sqrt(K[16][16])); prefix S built with a 6-step shfl scan
// held in wave-0 registers. Weights in closed form:
//   cell s covers pos [C(s), C(s+1)), C(s)=ceil(512 s/28)
//   w_d(y) = S[clamp(C(b+d+1)-y+16)] - S[clamp(C(b+d)-y+16)]
// SINGLE barrier: wave 0 builds S (LDS) + WY (LDS, via in-wave shfl lookups);
// waves load the patch; after the barrier every thread runs an independent
// read->fold->store pipeline (no staging, no second barrier, no convoy).
__device__ __forceinline__ int base_of(int y) {
    int p0 = y - PAD; if (p0 < 0) p0 = 0;
    int b = (p0 * PS) >> 9;              // floor(p0*28/512)
    return b > PS - 3 ? PS - 3 : b;
}
__device__ __forceinline__ int C_of(int s) {   // ceil(512*s/28)
    return (512 * s + 27) / 28;
}
__device__ __forceinline__ int clamp33(int i) {
    return min(max(i, 0), KS);
}

__global__ __launch_bounds__(256) void anomaly_fused(
        const float* __restrict__ p_in,
        const float* __restrict__ blur_w,
        float* __restrict__ out) {
    __shared__ float  S[KS + 1];                 // prefix of k1, S[0]=0
    __shared__ __align__(16) float P[PS * PS];   // 3.1 KB patch
    __shared__ float4 WY[RT];                    // per-row 4-tap u vs smin

    int t    = threadIdx.x;
    int b    = blockIdx.x >> 5;                  // / TILES
    int tile = blockIdx.x & (TILES - 1);
    int y0   = tile * RT;
    int smin = base_of(y0);

    // ---- patch load (196 float4, threads 0..195 across all waves)
    if (t < (PS * PS) / 4)
        ((float4*)P)[t] = ((const float4*)(p_in + (size_t)b * PS * PS))[t];

    // ---- wave 0: k1 scan in registers, emit S and WY (no cross-wave dep)
    if (t < 64) {
        float v = (t < KS) ? blur_w[t * KS + 16] : 0.f;   // K[t][16]
        float c = __shfl(v, 16);                 // K[16][16] = k1[16]^2
        float s = v / sqrtf(c);                  // k1[t] (0 for t>=33)
#pragma unroll
        for (int d = 1; d <= 32; d <<= 1) {      // inclusive scan
            float o = __shfl_up(s, (unsigned)d);
            if (t >= d) s += o;
        }
        if (t < KS)  S[t + 1] = s;               // S[i] = sum k1[0..i-1]
        if (t == 63) S[0] = 0.f;

        // WY: in-wave shfl lookup of S (lane l holds S[l+1])
        int y  = y0 + (t & (RT - 1));
        int by = base_of(y);
        int i0 = clamp33(C_of(by)     - y + PAD);
        int i1 = clamp33(C_of(by + 1) - y + PAD);
        int i2 = clamp33(C_of(by + 2) - y + PAD);
        int i3 = clamp33(C_of(by + 3) - y + PAD);
        float s0 = (i0 == 0) ? 0.f : __shfl(s, i0 - 1);
        float s1 = (i1 == 0) ? 0.f : __shfl(s, i1 - 1);
        float s2 = (i2 == 0) ? 0.f : __shfl(s, i2 - 1);
        float s3 = (i3 == 0) ? 0.f : __shfl(s, i3 - 1);
        if (t < RT) {
            float w0 = s1 - s0, w1 = s2 - s1, w2 = s3 - s2;
            int dy = by - smin;                  // 0 or 1
            WY[t] = make_float4(dy ? 0.f : w0,
                                dy ? w0  : w1,
                                dy ? w1  : w2,
                                dy ? w2  : 0.f);
        }
    }
    __syncthreads();

    // ---- free-running epilogue: per-thread fold + 8 nt stores
    int q    = t & 127;
    int half = t >> 7;
    int x0   = q * 4;

    float4 u[8];
#pragma unroll
    for (int r = 0; r < 8; ++r) u[r] = WY[half * 8 + r];  // uniform bcast

    // x-weights for 4 columns, closed form from S (16 LDS b32 reads)
    float wx[4][3];
    int   bx[4];
#pragma unroll
    for (int j = 0; j < 4; ++j) {
        int x = x0 + j;
        bx[j] = base_of(x);
        int i0 = clamp33(C_of(bx[j])     - x + PAD);
        int i1 = clamp33(C_of(bx[j] + 1) - x + PAD);
        int i2 = clamp33(C_of(bx[j] + 2) - x + PAD);
        int i3 = clamp33(C_of(bx[j] + 3) - x + PAD);
        float s0 = S[i0], s1 = S[i1], s2 = S[i2], s3 = S[i3];
        wx[j][0] = s1 - s0; wx[j][1] = s2 - s1; wx[j][2] = s3 - s2;
    }

    // x-blur of the 4 needed source rows (48 LDS b32 reads, reg results)
    float4 a[4];
#pragma unroll
    for (int i = 0; i < 4; ++i) {
        int sr = smin + i; if (sr > PS - 1) sr = PS - 1;  // weight 0 if OOB
        const float* pr = P + sr * PS;
        a[i].x = wx[0][0]*pr[bx[0]] + wx[0][1]*pr[bx[0]+1] + wx[0][2]*pr[bx[0]+2];
        a[i].y = wx[1][0]*pr[bx[1]] + wx[1][1]*pr[bx[1]+1] + wx[1][2]*pr[bx[1]+2];
        a[i].z = wx[2][0]*pr[bx[2]] + wx[2][1]*pr[bx[2]+1] + wx[2][2]*pr[bx[2]+2];
        a[i].w = wx[3][0]*pr[bx[3]] + wx[3][1]*pr[bx[3]+1] + wx[3][2]*pr[bx[3]+2];
    }

    float* obase = out + ((size_t)b * IMG + y0 + half * 8) * IMG + x0;
#pragma unroll
    for (int r = 0; r < 8; ++r) {
        vf4 acc;
        acc.x = u[r].x*a[0].x + u[r].y*a[1].x + u[r].z*a[2].x + u[r].w*a[3].x;
        acc.y = u[r].x*a[0].y + u[r].y*a[1].y + u[r].z*a[2].y + u[r].w*a[3].y;
        acc.z = u[r].x*a[0].z + u[r].y*a[1].z + u[r].z*a[2].z + u[r].w*a[3].z;
        acc.w = u[r].x*a[0].w + u[r].y*a[1].w + u[r].z*a[2].w + u[r].w*a[3].w;
        __builtin_nontemporal_store(acc, (vf4*)(obase + (size_t)r * IMG));
    }
}

extern "C" void kernel_launch(void* const* d_in, const int* in_sizes, int n_in,
                              void* d_out, int out_size, void* d_ws, size_t ws_size,
                              hipStream_t stream) {
    const float* patch = (const float*)d_in[0];
    const float* blur  = (const float*)d_in[1];
    float*       out   = (float*)d_out;

    int B = in_sizes[0] / (PS * PS);             // 32 images
    anomaly_fused<<<B * TILES, 256, 0, stream>>>(patch, blur, out);
}

// Round 8
// 13.068 us; speedup vs baseline: 1.3848x; 1.0248x over previous
//
#include <hip/hip_runtime.h>

#define IMG 512
#define PS  28      // patch spatial size
#define KS  33
#define PAD 16
#define RT  16      // output rows per block tile
#define TILES (IMG / RT)   // 32 tiles/image

typedef float vf4 __attribute__((ext_vector_type(4)));  // clang vector for nt-store

// out = Wy * (P * Wx^T): nearest-upsample + separable 33-tap blur collapses
// to <=3 taps per axis (a 33-tap window spans <=3 source cells of width
// >=18). k1 recovered from one COLUMN of blur_w (K[i][j]=k1[i]k1[j] =>
// k1[i]=K[i][16]/sqrt(K[16][16])); prefix S built with a 6-step shfl scan.
// Weights in closed form: cell s covers pos [C(s), C(s+1)), C(s)=ceil(512s/28)
//   w_d(y) = S[clamp(C(b+d+1)-y+16)] - S[clamp(C(b+d)-y+16)]
// Both axes use the 4-tap fold: 4 consecutive coords span <=2 cells, so a
// quad's 12 x-taps collapse onto 4 contiguous P words pr[bx0..bx0+3], and a
// 16-row tile's y-taps onto 4 source rows smin..smin+3. Epilogue per thread:
// 16 S-reads + 16 P-reads (was 64), then pure register FMA + 8 nt stores.
__device__ __forceinline__ int base_of(int y) {
    int p0 = y - PAD; if (p0 < 0) p0 = 0;
    int b = (p0 * PS) >> 9;              // floor(p0*28/512)
    return b > PS - 3 ? PS - 3 : b;
}
__device__ __forceinline__ int C_of(int s) {   // ceil(512*s/28)
    return (512 * s + 27) / 28;
}
__device__ __forceinline__ int clamp33(int i) {
    return min(max(i, 0), KS);
}

__global__ __launch_bounds__(256) void anomaly_fused(
        const float* __restrict__ p_in,
        const float* __restrict__ blur_w,
        float* __restrict__ out) {
    __shared__ float  S[KS + 1];                     // prefix of k1, S[0]=0
    __shared__ __align__(16) float P[PS * PS + 4];   // patch + 4-word zero pad
    __shared__ float4 WY[RT];                        // per-row 4-tap u vs smin

    int t    = threadIdx.x;
    int b    = blockIdx.x >> 5;                  // / TILES
    int tile = blockIdx.x & (TILES - 1);
    int y0   = tile * RT;
    int smin = base_of(y0);

    // ---- patch load (196 float4) + zero the pad word
    if (t < (PS * PS) / 4)
        ((float4*)P)[t] = ((const float4*)(p_in + (size_t)b * PS * PS))[t];
    if (t == 196)
        ((float4*)P)[196] = make_float4(0.f, 0.f, 0.f, 0.f);

    // ---- wave 0: k1 scan in registers, emit S and WY (no cross-wave dep)
    if (t < 64) {
        float v = (t < KS) ? blur_w[t * KS + 16] : 0.f;   // K[t][16]
        float c = __shfl(v, 16);                 // K[16][16] = k1[16]^2
        float s = v / sqrtf(c);                  // k1[t] (0 for t>=33)
#pragma unroll
        for (int d = 1; d <= 32; d <<= 1) {      // inclusive scan
            float o = __shfl_up(s, (unsigned)d);
            if (t >= d) s += o;
        }
        if (t < KS)  S[t + 1] = s;               // S[i] = sum k1[0..i-1]
        if (t == 63) S[0] = 0.f;

        // WY: in-wave shfl lookup of S (lane l holds S[l+1])
        int y  = y0 + (t & (RT - 1));
        int by = base_of(y);
        int i0 = clamp33(C_of(by)     - y + PAD);
        int i1 = clamp33(C_of(by + 1) - y + PAD);
        int i2 = clamp33(C_of(by + 2) - y + PAD);
        int i3 = clamp33(C_of(by + 3) - y + PAD);
        float s0 = (i0 == 0) ? 0.f : __shfl(s, i0 - 1);
        float s1 = (i1 == 0) ? 0.f : __shfl(s, i1 - 1);
        float s2 = (i2 == 0) ? 0.f : __shfl(s, i2 - 1);
        float s3 = (i3 == 0) ? 0.f : __shfl(s, i3 - 1);
        if (t < RT) {
            float w0 = s1 - s0, w1 = s2 - s1, w2 = s3 - s2;
            int dy = by - smin;                  // 0 or 1
            WY[t] = make_float4(dy ? 0.f : w0,
                                dy ? w0  : w1,
                                dy ? w1  : w2,
                                dy ? w2  : 0.f);
        }
    }
    __syncthreads();

    // ---- free-running epilogue: per-thread fold + 8 nt stores
    int q    = t & 127;
    int half = t >> 7;
    int x0   = q * 4;

    float4 u[8];
#pragma unroll
    for (int r = 0; r < 8; ++r) u[r] = WY[half * 8 + r];  // uniform bcast

    // x-weights folded to 4 taps relative to bx0 = base_of(x0)
    // (bx[j] - bx0 in {0,1} since 4 consecutive x span <=2 cells)
    int bx0 = base_of(x0);
    float4 vx[4];
#pragma unroll
    for (int j = 0; j < 4; ++j) {
        int x  = x0 + j;
        int bx = base_of(x);
        int i0 = clamp33(C_of(bx)     - x + PAD);
        int i1 = clamp33(C_of(bx + 1) - x + PAD);
        int i2 = clamp33(C_of(bx + 2) - x + PAD);
        int i3 = clamp33(C_of(bx + 3) - x + PAD);
        float s0 = S[i0], s1 = S[i1], s2 = S[i2], s3 = S[i3];
        float w0 = s1 - s0, w1 = s2 - s1, w2 = s3 - s2;
        int dj = bx - bx0;                       // 0 or 1
        vx[j] = make_float4(dj ? 0.f : w0,
                            dj ? w0  : w1,
                            dj ? w1  : w2,
                            dj ? w2  : 0.f);
    }

    // x-blur of the 4 needed source rows: 4 contiguous P words per row
    float4 a[4];
#pragma unroll
    for (int i = 0; i < 4; ++i) {
        int sr = smin + i; if (sr > PS - 1) sr = PS - 1;  // weight 0 if OOB
        const float* pr = P + sr * PS + bx0;
        float p0 = pr[0], p1 = pr[1], p2 = pr[2], p3 = pr[3];
        a[i].x = vx[0].x*p0 + vx[0].y*p1 + vx[0].z*p2 + vx[0].w*p3;
        a[i].y = vx[1].x*p0 + vx[1].y*p1 + vx[1].z*p2 + vx[1].w*p3;
        a[i].z = vx[2].x*p0 + vx[2].y*p1 + vx[2].z*p2 + vx[2].w*p3;
        a[i].w = vx[3].x*p0 + vx[3].y*p1 + vx[3].z*p2 + vx[3].w*p3;
    }

    float* obase = out + ((size_t)b * IMG + y0 + half * 8) * IMG + x0;
#pragma unroll
    for (int r = 0; r < 8; ++r) {
        vf4 acc;
        acc.x = u[r].x*a[0].x + u[r].y*a[1].x + u[r].z*a[2].x + u[r].w*a[3].x;
        acc.y = u[r].x*a[0].y + u[r].y*a[1].y + u[r].z*a[2].y + u[r].w*a[3].y;
        acc.z = u[r].x*a[0].z + u[r].y*a[1].z + u[r].z*a[2].z + u[r].w*a[3].z;
        acc.w = u[r].x*a[0].w + u[r].y*a[1].w + u[r].z*a[2].w + u[r].w*a[3].w;
        __builtin_nontemporal_store(acc, (vf4*)(obase + (size_t)r * IMG));
    }
}

extern "C" void kernel_launch(void* const* d_in, const int* in_sizes, int n_in,
                              void* d_out, int out_size, void* d_ws, size_t ws_size,
                              hipStream_t stream) {
    const float* patch = (const float*)d_in[0];
    const float* blur  = (const float*)d_in[1];
    float*       out   = (float*)d_out;

    int B = in_sizes[0] / (PS * PS);             // 32 images
    anomaly_fused<<<B * TILES, 256, 0, stream>>>(patch, blur, out);
}

// Round 9
// 12.724 us; speedup vs baseline: 1.4222x; 1.0270x over previous
//
#include <hip/hip_runtime.h>

#define IMG 512
#define PS  28      // patch spatial size
#define KS  33
#define PAD 16
#define RT  32      // output rows per block tile
#define TILES (IMG / RT)   // 16 tiles/image

typedef float vf4 __attribute__((ext_vector_type(4)));  // clang vector for nt-store

// out = Wy * (P * Wx^T): nearest-upsample + separable 33-tap blur collapses
// to <=3 taps per axis (a 33-tap window spans <=3 source cells of width
// >=18). k1 recovered from one COLUMN of blur_w (K[i][j]=k1[i]k1[j] =>
// k1[i]=K[i][16]/sqrt(K[16][16])); prefix S built with a 6-step shfl scan.
// Weights in closed form: cell s covers pos [C(s), C(s+1)), C(s)=ceil(512s/28)
//   w_d(y) = S[clamp(C(b+d+1)-y+16)] - S[clamp(C(b+d)-y+16)]
// 4-tap folds on both axes; y-fold is per-OCTANT (8 consecutive rows span
// <=2 source cells, so dy = by - smin_oct in {0,1}). 512-thread blocks:
// thread = (octant = t>>7, column-quad q = t&127); per-thread epilogue =
// 16 S-reads + 16 P-reads + reg FMA + 8 nt stores. One barrier.
__device__ __forceinline__ int base_of(int y) {
    int p0 = y - PAD; if (p0 < 0) p0 = 0;
    int b = (p0 * PS) >> 9;              // floor(p0*28/512)
    return b > PS - 3 ? PS - 3 : b;
}
__device__ __forceinline__ int C_of(int s) {   // ceil(512*s/28)
    return (512 * s + 27) / 28;
}
__device__ __forceinline__ int clamp33(int i) {
    return min(max(i, 0), KS);
}

__global__ __launch_bounds__(512) void anomaly_fused(
        const float* __restrict__ p_in,
        const float* __restrict__ blur_w,
        float* __restrict__ out) {
    __shared__ float  S[KS + 1];                     // prefix of k1, S[0]=0
    __shared__ __align__(16) float P[PS * PS + 4];   // patch + 4-word zero pad
    __shared__ float4 WY[RT];                        // per-row 4-tap u vs octant smin

    int t    = threadIdx.x;
    int b    = blockIdx.x >> 4;                  // / TILES
    int tile = blockIdx.x & (TILES - 1);
    int y0   = tile * RT;

    // ---- patch load (196 float4) + zero the pad word
    if (t < (PS * PS) / 4)
        ((float4*)P)[t] = ((const float4*)(p_in + (size_t)b * PS * PS))[t];
    if (t == 196)
        ((float4*)P)[196] = make_float4(0.f, 0.f, 0.f, 0.f);

    // ---- wave 0: k1 scan in registers, emit S and WY[32] (in-wave only)
    if (t < 64) {
        float v = (t < KS) ? blur_w[t * KS + 16] : 0.f;   // K[t][16]
        float c = __shfl(v, 16);                 // K[16][16] = k1[16]^2
        float s = v / sqrtf(c);                  // k1[t] (0 for t>=33)
#pragma unroll
        for (int d = 1; d <= 32; d <<= 1) {      // inclusive scan
            float o = __shfl_up(s, (unsigned)d);
            if (t >= d) s += o;
        }
        if (t < KS)  S[t + 1] = s;               // S[i] = sum k1[0..i-1]
        if (t == 63) S[0] = 0.f;

        // WY: lane l handles tile-row l (l<32); fold vs ITS octant's smin
        int rl = t & (RT - 1);
        int y  = y0 + rl;
        int by = base_of(y);
        int i0 = clamp33(C_of(by)     - y + PAD);
        int i1 = clamp33(C_of(by + 1) - y + PAD);
        int i2 = clamp33(C_of(by + 2) - y + PAD);
        int i3 = clamp33(C_of(by + 3) - y + PAD);
        float s0 = (i0 == 0) ? 0.f : __shfl(s, i0 - 1);
        float s1 = (i1 == 0) ? 0.f : __shfl(s, i1 - 1);
        float s2 = (i2 == 0) ? 0.f : __shfl(s, i2 - 1);
        float s3 = (i3 == 0) ? 0.f : __shfl(s, i3 - 1);
        if (t < RT) {
            float w0 = s1 - s0, w1 = s2 - s1, w2 = s3 - s2;
            int smin_o = base_of(y0 + (rl & ~7));    // octant start row
            int dy = by - smin_o;                    // 0 or 1
            WY[t] = make_float4(dy ? 0.f : w0,
                                dy ? w0  : w1,
                                dy ? w1  : w2,
                                dy ? w2  : 0.f);
        }
    }
    __syncthreads();

    // ---- free-running epilogue: per-thread fold + 8 nt stores
    int q   = t & 127;
    int oct = t >> 7;                            // 0..3, wave-uniform
    int x0  = q * 4;
    int ys  = y0 + oct * 8;
    int smin = base_of(ys);                      // octant's first source row

    float4 u[8];
#pragma unroll
    for (int r = 0; r < 8; ++r) u[r] = WY[oct * 8 + r];   // uniform bcast

    // x-weights folded to 4 taps relative to bx0 = base_of(x0)
    int bx0 = base_of(x0);
    float4 vx[4];
#pragma unroll
    for (int j = 0; j < 4; ++j) {
        int x  = x0 + j;
        int bx = base_of(x);
        int i0 = clamp33(C_of(bx)     - x + PAD);
        int i1 = clamp33(C_of(bx + 1) - x + PAD);
        int i2 = clamp33(C_of(bx + 2) - x + PAD);
        int i3 = clamp33(C_of(bx + 3) - x + PAD);
        float s0 = S[i0], s1 = S[i1], s2 = S[i2], s3 = S[i3];
        float w0 = s1 - s0, w1 = s2 - s1, w2 = s3 - s2;
        int dj = bx - bx0;                       // 0 or 1
        vx[j] = make_float4(dj ? 0.f : w0,
                            dj ? w0  : w1,
                            dj ? w1  : w2,
                            dj ? w2  : 0.f);
    }

    // x-blur of the 4 needed source rows: 4 contiguous P words per row
    float4 a[4];
#pragma unroll
    for (int i = 0; i < 4; ++i) {
        int sr = smin + i; if (sr > PS - 1) sr = PS - 1;  // weight 0 if OOB
        const float* pr = P + sr * PS + bx0;
        float p0 = pr[0], p1 = pr[1], p2 = pr[2], p3 = pr[3];
        a[i].x = vx[0].x*p0 + vx[0].y*p1 + vx[0].z*p2 + vx[0].w*p3;
        a[i].y = vx[1].x*p0 + vx[1].y*p1 + vx[1].z*p2 + vx[1].w*p3;
        a[i].z = vx[2].x*p0 + vx[2].y*p1 + vx[2].z*p2 + vx[2].w*p3;
        a[i].w = vx[3].x*p0 + vx[3].y*p1 + vx[3].z*p2 + vx[3].w*p3;
    }

    float* obase = out + ((size_t)b * IMG + ys) * IMG + x0;
#pragma unroll
    for (int r = 0; r < 8; ++r) {
        vf4 acc;
        acc.x = u[r].x*a[0].x + u[r].y*a[1].x + u[r].z*a[2].x + u[r].w*a[3].x;
        acc.y = u[r].x*a[0].y + u[r].y*a[1].y + u[r].z*a[2].y + u[r].w*a[3].y;
        acc.z = u[r].x*a[0].z + u[r].y*a[1].z + u[r].z*a[2].z + u[r].w*a[3].z;
        acc.w = u[r].x*a[0].w + u[r].y*a[1].w + u[r].z*a[2].w + u[r].w*a[3].w;
        __builtin_nontemporal_store(acc, (vf4*)(obase + (size_t)r * IMG));
    }
}

extern "C" void kernel_launch(void* const* d_in, const int* in_sizes, int n_in,
                              void* d_out, int out_size, void* d_ws, size_t ws_size,
                              hipStream_t stream) {
    const float* patch = (const float*)d_in[0];
    const float* blur  = (const float*)d_in[1];
    float*       out   = (float*)d_out;

    int B = in_sizes[0] / (PS * PS);             // 32 images
    anomaly_fused<<<B * TILES, 512, 0, stream>>>(patch, blur, out);
}